// Round 7
// baseline (1253.193 us; speedup 1.0000x reference)
//
#include <hip/hip_runtime.h>

// Sparse UNet, fp16 — uniform 8-channel phase gathers + deep MLP.
//  - s=(bid>>2)&1 stream->XCD partition (validated R6: conv2 FETCH 805->349MB)
//  - ALL gather passes use 8-ch (16B row) tables: 1.92MB per XCD (48% of L2)
//    conv1: 1 pass; conv2: 2 half passes; conv3: 4 quarter passes.
//    Later passes accumulate into the fp16 partial in place (stream order
//    serializes dispatches -> time-phased tables, no combine kernels).
//  - 9-deep gather pipeline: indices loaded in static groups of 9, two groups
//    of row-gathers in flight before the first dot block (counted vmcnt).
//  - nt loads for nbr, nt stores for outputs; plain cached loads for gathers.
//  - BN stats epilogue on the final pass of each conv; apply pass writes
//    8-ch split tables for the next layer. Head is linear -> per-batch sums.

#define DEVI __device__ __forceinline__

typedef _Float16 h2 __attribute__((ext_vector_type(2)));
typedef unsigned u4 __attribute__((ext_vector_type(4)));

constexpr int KNBR = 27;

DEVI h2 bch2(unsigned u) { return __builtin_bit_cast(h2, u); }
DEVI unsigned pkh2(float a, float b) {
    h2 v; v.x = (_Float16)a; v.y = (_Float16)b;
    return __builtin_bit_cast(unsigned, v);
}
DEVI float bnr(float x, float sc, float sh) {
    float y = fmaf(x, sc, sh);
    return y > 0.f ? y : 0.f;
}

// ---------------- prep ----------------

// b0: W1 [k][6][16]  -> [k][16][8]
// b1: W2 [k][16][32] -> [h:2][k][32][8]   (h = input-channel half)
// b2: W3 [k][32][16] -> [q:4][k][16][8]   (q = input-channel quarter)
// b3: zero bsum
__global__ __launch_bounds__(256)
void prep_weights_kernel(const float* __restrict__ W1, const float* __restrict__ W2,
                         const float* __restrict__ W3,
                         _Float16* __restrict__ w1t, _Float16* __restrict__ w2t,
                         _Float16* __restrict__ w3t,
                         float* __restrict__ bsum, int nb)
{
    const int b = blockIdx.x;
    if (b == 3) {
        for (int i = threadIdx.x; i < nb; i += 256) bsum[i] = 0.f;
        return;
    }
    if (b == 0) {
        for (int i = threadIdx.x; i < KNBR * 16 * 8; i += 256) {
            const int c = i % 8, d = (i / 8) % 16, k = i / 128;
            w1t[i] = (_Float16)((c < 6) ? W1[(k * 6 + c) * 16 + d] : 0.f);
        }
    } else if (b == 1) {
        for (int i = threadIdx.x; i < 2 * KNBR * 32 * 8; i += 256) {
            const int c = i % 8, d = (i / 8) % 32, k = (i / 256) % KNBR, h = i / (256 * KNBR);
            w2t[i] = (_Float16)W2[(k * 16 + h * 8 + c) * 32 + d];
        }
    } else {
        for (int i = threadIdx.x; i < 4 * KNBR * 16 * 8; i += 256) {
            const int c = i % 8, d = (i / 8) % 16, k = (i / 128) % KNBR, q = i / (128 * KNBR);
            w3t[i] = (_Float16)W3[(k * 32 + q * 8 + c) * 16 + d];
        }
    }
}

// fp32 [N][6] -> fp16 [s][(N+1)][8] (pad channels, zero row N)
__global__ __launch_bounds__(256)
void prep_feats_kernel(const float* __restrict__ f0, const float* __restrict__ f1,
                       _Float16* __restrict__ o, int N)
{
    const int s = blockIdx.y;
    const float* __restrict__ f = s ? f1 : f0;
    _Float16* __restrict__ out = o + (size_t)s * (N + 1) * 8;
    const int n = blockIdx.x * 256 + threadIdx.x;
    if (n < N) {
        const float2* r = (const float2*)(f + (size_t)n * 6);
        float2 a = r[0], b = r[1], c = r[2];
        u4 w;
        w.x = pkh2(a.x, a.y);
        w.y = pkh2(b.x, b.y);
        w.z = pkh2(c.x, c.y);
        w.w = 0u;
        ((u4*)out)[n] = w;
    } else if (n == N) {
        ((u4*)out)[n] = (u4){0u, 0u, 0u, 0u};
    }
}

// ---------------- 8-channel gather conv pass ----------------
// feats: [s][(N+1)][8] (this phase's table), Wt: [27][COUT][8]
// outp:  [s][(N+1)][COUT] fp16 partial (ACCUM: += )

#define DOT9(R, G0)                                                            \
    _Pragma("unroll")                                                          \
    for (int j = 0; j < 9; ++j) {                                              \
        _Pragma("unroll")                                                      \
        for (int d = 0; d < COUT; ++d) {                                       \
            const u4 wv = wp[(G0 + j) * COUT + d];                             \
            acc[d] = __builtin_amdgcn_fdot2(bch2(R[j].x), bch2(wv.x), acc[d], false); \
            acc[d] = __builtin_amdgcn_fdot2(bch2(R[j].y), bch2(wv.y), acc[d], false); \
            acc[d] = __builtin_amdgcn_fdot2(bch2(R[j].z), bch2(wv.z), acc[d], false); \
            acc[d] = __builtin_amdgcn_fdot2(bch2(R[j].w), bch2(wv.w), acc[d], false); \
        }                                                                      \
    }

template<int COUT, bool ACCUM, bool STATS>
__global__ __launch_bounds__(256)
void conv8(const _Float16* __restrict__ feats,
           const int* __restrict__ nb0, const int* __restrict__ nb1,
           const _Float16* __restrict__ Wt,
           _Float16* __restrict__ outp,
           float* __restrict__ partials, int N, int B)
{
    constexpr int WU4 = KNBR * COUT;
    const int bid = blockIdx.x;
    const int s = (bid >> 2) & 1;            // XCD-robust stream partition
    const int vb = (bid >> 3) * 4 + (bid & 3);
    if (vb >= B) return;
    const int tid = threadIdx.x;

    __shared__ __align__(16) _Float16 wl[KNBR * COUT * 8];
    __shared__ float sred[4][64];
    for (int i = tid; i < WU4; i += 256) ((u4*)wl)[i] = ((const u4*)Wt)[i];
    __syncthreads();
    const u4* wp = (const u4*)wl;

    const size_t stride = (size_t)N + 1;
    const _Float16* __restrict__ fs = feats + (size_t)s * stride * 8;
    const int* __restrict__ nbr = s ? nb1 : nb0;
    const int n = vb * 256 + tid;
    const bool act = n < N;
    const int* nrow = nbr + (size_t)(act ? n : 0) * KNBR;

    float acc[COUT];
    #pragma unroll
    for (int d = 0; d < COUT; ++d) acc[d] = 0.f;

    // 3 groups of 9, software-pipelined: group g+1's gathers are in flight
    // while group g's dots execute (compiler emits counted vmcnt).
    int ia[9], ib[9], ic[9];
    u4 ra[9], rb[9], rc[9];
    #pragma unroll
    for (int j = 0; j < 9; ++j) ia[j] = act ? __builtin_nontemporal_load(nrow + j) : N;
    #pragma unroll
    for (int j = 0; j < 9; ++j) ra[j] = *(const u4*)(fs + (size_t)ia[j] * 8);
    #pragma unroll
    for (int j = 0; j < 9; ++j) ib[j] = act ? __builtin_nontemporal_load(nrow + 9 + j) : N;
    #pragma unroll
    for (int j = 0; j < 9; ++j) rb[j] = *(const u4*)(fs + (size_t)ib[j] * 8);

    DOT9(ra, 0)

    #pragma unroll
    for (int j = 0; j < 9; ++j) ic[j] = act ? __builtin_nontemporal_load(nrow + 18 + j) : N;
    #pragma unroll
    for (int j = 0; j < 9; ++j) rc[j] = *(const u4*)(fs + (size_t)ic[j] * 8);

    DOT9(rb, 9)
    DOT9(rc, 18)

    if constexpr (ACCUM) {
        if (act) {
            const u4* prow = (const u4*)(outp + ((size_t)s * stride + n) * COUT);
            #pragma unroll
            for (int q = 0; q < COUT / 8; ++q) {
                const u4 v = prow[q];
                h2 x;
                x = bch2(v.x); acc[8 * q + 0] += (float)x.x; acc[8 * q + 1] += (float)x.y;
                x = bch2(v.y); acc[8 * q + 2] += (float)x.x; acc[8 * q + 3] += (float)x.y;
                x = bch2(v.z); acc[8 * q + 4] += (float)x.x; acc[8 * q + 5] += (float)x.y;
                x = bch2(v.w); acc[8 * q + 6] += (float)x.x; acc[8 * q + 7] += (float)x.y;
            }
        }
    }

    if (act) {
        u4* orow = (u4*)(outp + ((size_t)s * stride + n) * COUT);
        #pragma unroll
        for (int q = 0; q < COUT / 8; ++q) {
            u4 v = {pkh2(acc[8 * q + 0], acc[8 * q + 1]), pkh2(acc[8 * q + 2], acc[8 * q + 3]),
                    pkh2(acc[8 * q + 4], acc[8 * q + 5]), pkh2(acc[8 * q + 6], acc[8 * q + 7])};
            __builtin_nontemporal_store(v, orow + q);
        }
    }

    if constexpr (STATS) {
        float ts[COUT], tq[COUT];
        #pragma unroll
        for (int d = 0; d < COUT; ++d) { ts[d] = acc[d]; tq[d] = acc[d] * acc[d]; }
        #pragma unroll
        for (int d = 0; d < COUT; ++d) {
            #pragma unroll
            for (int m = 32; m >= 1; m >>= 1) {
                ts[d] += __shfl_xor(ts[d], m);
                tq[d] += __shfl_xor(tq[d], m);
            }
        }
        const int lane = tid & 63, wid = tid >> 6;
        if (lane == 0) {
            #pragma unroll
            for (int d = 0; d < COUT; ++d) { sred[wid][d] = ts[d]; sred[wid][COUT + d] = tq[d]; }
        }
        __syncthreads();
        if (tid < 2 * COUT) {
            float tot = sred[0][tid] + sred[1][tid] + sred[2][tid] + sred[3][tid];
            partials[((size_t)s * B + vb) * 64 + tid] = tot;
        }
    }
}

// ---------------- BN stats -> scale/shift ----------------

template<int COUT>
__global__ __launch_bounds__(256)
void stats_kernel(const float* __restrict__ partials, int B, int N,
                  const float* __restrict__ g, const float* __restrict__ b,
                  float* __restrict__ ss)
{
    const int s = blockIdx.y;
    const int tid = threadIdx.x;
    const float* P = partials + (size_t)s * B * 64;
    const int q = tid & 63;
    const int ch = tid >> 6;
    float a = 0.f;
    for (int i = ch; i < B; i += 4) a += P[(size_t)i * 64 + q];
    __shared__ float red[256];
    red[tid] = a;
    __syncthreads();
    if (tid < 64) red[tid] = red[tid] + red[64 + tid] + red[128 + tid] + red[192 + tid];
    __syncthreads();
    if (tid < COUT) {
        float sum = red[tid];
        float sq = red[COUT + tid];
        float mean = sum / (float)N;
        float var = sq / (float)N - mean * mean;
        float scl = g[tid] * rsqrtf(var + 1e-4f);
        float sft = b[tid] - mean * scl;
        float* ssp = ss + s * 64;
        ssp[tid] = scl;
        ssp[32 + tid] = sft;
    }
}

// ---------------- apply BN+ReLU, write 8-ch split tables [ph][s][str][8] ----------------

template<int COUT>
__global__ __launch_bounds__(256)
void apply_split_kernel(const _Float16* __restrict__ pre, _Float16* __restrict__ post,
                        const float* __restrict__ ss, int N)
{
    constexpr int CH8 = COUT / 8;
    const int s = blockIdx.y;
    const size_t stride = (size_t)N + 1;
    __shared__ float sc[32], sh[32];
    if (threadIdx.x < COUT) {
        sc[threadIdx.x] = ss[s * 64 + threadIdx.x];
        sh[threadIdx.x] = ss[s * 64 + 32 + threadIdx.x];
    }
    __syncthreads();
    const long long chunks = (long long)stride * CH8;
    const long long i = (long long)blockIdx.x * 256 + threadIdx.x;
    if (i >= chunks) return;
    const int row = (int)(i / CH8);
    const int ph8 = (int)(i % CH8);
    const int cb = ph8 * 8;
    const u4 v = __builtin_nontemporal_load((const u4*)pre + (size_t)s * stride * CH8 + i);
    u4 r;
    {
        h2 x0 = bch2(v.x), x1 = bch2(v.y), x2 = bch2(v.z), x3 = bch2(v.w);
        r.x = pkh2(bnr((float)x0.x, sc[cb + 0], sh[cb + 0]), bnr((float)x0.y, sc[cb + 1], sh[cb + 1]));
        r.y = pkh2(bnr((float)x1.x, sc[cb + 2], sh[cb + 2]), bnr((float)x1.y, sc[cb + 3], sh[cb + 3]));
        r.z = pkh2(bnr((float)x2.x, sc[cb + 4], sh[cb + 4]), bnr((float)x2.y, sc[cb + 5], sh[cb + 5]));
        r.w = pkh2(bnr((float)x3.x, sc[cb + 6], sh[cb + 6]), bnr((float)x3.y, sc[cb + 7], sh[cb + 7]));
    }
    if (row >= N) r = (u4){0u, 0u, 0u, 0u};
    __builtin_nontemporal_store(r, (u4*)post + (size_t)(ph8 * 2 + s) * stride + row);
}

// ---------------- point gather + per-batch channel sums (BN3 inline) ----------------

__global__ __launch_bounds__(256)
void pointsum_kernel(const _Float16* __restrict__ h3,  // [s][(N+1)][16] pre-BN fp16
                     const int* __restrict__ id0, const int* __restrict__ id1,
                     const float* __restrict__ ss, float* __restrict__ bsum,
                     int N, int Ppb, int bpb, int bs, int PB)
{
    const int bid = blockIdx.x;
    const int s = (bid >> 2) & 1;
    const int pb = (bid >> 3) * 4 + (bid & 3);
    if (pb >= PB) return;
    const int batch = pb / bpb;
    const int blk = pb % bpb;

    const _Float16* __restrict__ h = h3 + (size_t)s * (N + 1) * 16;
    const int* __restrict__ ids = s ? id1 : id0;

    const float* ssp = ss + s * 64;
    float sc[16], sh[16];
    #pragma unroll
    for (int c = 0; c < 16; ++c) { sc[c] = ssp[c]; sh[c] = ssp[32 + c]; }

    float acc[16];
    #pragma unroll
    for (int c = 0; c < 16; ++c) acc[c] = 0.f;

    const int* bid_p = ids + (size_t)batch * Ppb;
    const int base = blk * (256 * 8) + threadIdx.x;
    for (int i = 0; i < 8; ++i) {
        int off = base + i * 256;
        if (off < Ppb) {
            int vx = __builtin_nontemporal_load(bid_p + off);
            const u4* r = (const u4*)(h + (size_t)vx * 16);
            u4 a = r[0], b = r[1];
            h2 x;
            x = bch2(a.x); acc[0] += bnr((float)x.x, sc[0], sh[0]);   acc[1] += bnr((float)x.y, sc[1], sh[1]);
            x = bch2(a.y); acc[2] += bnr((float)x.x, sc[2], sh[2]);   acc[3] += bnr((float)x.y, sc[3], sh[3]);
            x = bch2(a.z); acc[4] += bnr((float)x.x, sc[4], sh[4]);   acc[5] += bnr((float)x.y, sc[5], sh[5]);
            x = bch2(a.w); acc[6] += bnr((float)x.x, sc[6], sh[6]);   acc[7] += bnr((float)x.y, sc[7], sh[7]);
            x = bch2(b.x); acc[8] += bnr((float)x.x, sc[8], sh[8]);   acc[9] += bnr((float)x.y, sc[9], sh[9]);
            x = bch2(b.y); acc[10] += bnr((float)x.x, sc[10], sh[10]); acc[11] += bnr((float)x.y, sc[11], sh[11]);
            x = bch2(b.z); acc[12] += bnr((float)x.x, sc[12], sh[12]); acc[13] += bnr((float)x.y, sc[13], sh[13]);
            x = bch2(b.w); acc[14] += bnr((float)x.x, sc[14], sh[14]); acc[15] += bnr((float)x.y, sc[15], sh[15]);
        }
    }

    #pragma unroll
    for (int c = 0; c < 16; ++c) {
        #pragma unroll
        for (int m = 32; m >= 1; m >>= 1) acc[c] += __shfl_xor(acc[c], m);
    }
    __shared__ float sred[4][16];
    const int lane = threadIdx.x & 63, wid = threadIdx.x >> 6;
    if (lane == 0) {
        #pragma unroll
        for (int c = 0; c < 16; ++c) sred[wid][c] = acc[c];
    }
    __syncthreads();
    if (threadIdx.x < 16) {
        float tot = sred[0][threadIdx.x] + sred[1][threadIdx.x] + sred[2][threadIdx.x] + sred[3][threadIdx.x];
        atomicAdd(&bsum[((size_t)s * bs + batch) * 16 + threadIdx.x], tot);
    }
}

// ---------------- head ----------------

__global__ void final_kernel(const float* __restrict__ bsum,
                             const float* __restrict__ Wg, const float* __restrict__ bg,
                             const float* __restrict__ Wr, const float* __restrict__ br,
                             float* __restrict__ out, int bs, float invP)
{
    const int t = threadIdx.x;
    const int total = 4 * bs * 3;
    if (t < total) {
        const int x = t % 3;
        const int b = (t / 3) % bs;
        const int r = t / (3 * bs);
        const int s = r & 1;
        const float* W = (r < 2) ? Wg : Wr;
        const float* bias = (r < 2) ? bg : br;
        const float* m = bsum + ((size_t)s * bs + b) * 16;
        float a = bias[x];
        #pragma unroll
        for (int c = 0; c < 16; ++c) a = fmaf(m[c] * invP, W[c * 3 + x], a);
        out[t] = a;
    }
}

// ---------------- launch ----------------

extern "C" void kernel_launch(void* const* d_in, const int* in_sizes, int n_in,
                              void* d_out, int out_size, void* d_ws, size_t ws_size,
                              hipStream_t stream)
{
    (void)n_in; (void)ws_size;
    const float* vf0 = (const float*)d_in[0];
    const int*   nb0 = (const int*)d_in[1];
    const int*   id0 = (const int*)d_in[2];
    const float* vf1 = (const float*)d_in[3];
    const int*   nb1 = (const int*)d_in[4];
    const int*   id1 = (const int*)d_in[5];
    const float* W1 = (const float*)d_in[7];
    const float* g1 = (const float*)d_in[8];
    const float* b1 = (const float*)d_in[9];
    const float* W2 = (const float*)d_in[10];
    const float* g2 = (const float*)d_in[11];
    const float* b2 = (const float*)d_in[12];
    const float* W3 = (const float*)d_in[13];
    const float* g3 = (const float*)d_in[14];
    const float* b3 = (const float*)d_in[15];
    const float* Wg = (const float*)d_in[16];
    const float* bg = (const float*)d_in[17];
    const float* Wr = (const float*)d_in[18];
    const float* br = (const float*)d_in[19];

    const int N = in_sizes[0] / 6;       // 120000
    const int npts = in_sizes[2];        // bs * P
    const int bs = out_size / 12;        // out = [4, bs, 3]
    const int Ppb = npts / bs;
    const size_t stride = (size_t)N + 1;
    const int B = (N + 255) / 256;
    const int B4 = ((B + 3) / 4) * 4;

    // Arena (halves), lifetime reuse:
    //  A [64*str]: pre2 accum [s][str][32]
    //  C [64*str]: fin [s][str][8] + pre1 [s][str][16] -> post2 [q:4][s][str][8]
    //  D [32*str]: post1 [h:2][s][str][8]
    //  E [32*str]: pre3 accum [s][str][16]
    _Float16* A   = (_Float16*)d_ws;
    _Float16* C   = A + 64 * stride;
    _Float16* D   = C + 64 * stride;
    _Float16* E   = D + 32 * stride;
    _Float16* w1t = E + 32 * stride;                    // 3456
    _Float16* w2t = w1t + KNBR * 16 * 8;                // 13824
    _Float16* w3t = w2t + 2 * KNBR * 32 * 8;            // 13824
    float* partials = (float*)(w3t + 4 * KNBR * 16 * 8);   // 2*B*64
    float* ssb  = partials + (size_t)2 * B * 64;        // 128
    float* bsum = ssb + 128;                            // 2*bs*16

    _Float16* fin   = C;
    _Float16* pre1  = C + 16 * stride;
    _Float16* post1 = D;            // [h:2][s][str][8]
    _Float16* pre2  = A;            // [s][str][32]
    _Float16* post2 = C;            // [q:4][s][str][8]
    _Float16* pre3  = E;            // [s][str][16]

    prep_feats_kernel<<<dim3((unsigned)((stride + 255) / 256), 2), 256, 0, stream>>>(vf0, vf1, fin, N);
    prep_weights_kernel<<<4, 256, 0, stream>>>(W1, W2, W3, w1t, w2t, w3t, bsum, 2 * bs * 16);

    // conv1: fin -> pre1 (+stats)
    conv8<16, false, true><<<2 * B4, 256, 0, stream>>>(fin, nb0, nb1, w1t, pre1, partials, N, B);
    stats_kernel<16><<<dim3(1, 2), 256, 0, stream>>>(partials, B, N, g1, b1, ssb);
    apply_split_kernel<16><<<dim3((unsigned)((stride * 2 + 255) / 256), 2), 256, 0, stream>>>(pre1, post1, ssb, N);

    // conv2: two 8-ch half passes, second accumulates (+stats)
    conv8<32, false, false><<<2 * B4, 256, 0, stream>>>(post1, nb0, nb1, w2t, pre2, nullptr, N, B);
    conv8<32, true, true><<<2 * B4, 256, 0, stream>>>(post1 + 2 * stride * 8, nb0, nb1,
                                                      w2t + KNBR * 32 * 8, pre2, partials, N, B);
    stats_kernel<32><<<dim3(1, 2), 256, 0, stream>>>(partials, B, N, g2, b2, ssb);
    apply_split_kernel<32><<<dim3((unsigned)((stride * 4 + 255) / 256), 2), 256, 0, stream>>>(pre2, post2, ssb, N);

    // conv3: four 8-ch quarter passes, later ones accumulate, last does stats
    conv8<16, false, false><<<2 * B4, 256, 0, stream>>>(post2, nb0, nb1, w3t, pre3, nullptr, N, B);
    conv8<16, true, false><<<2 * B4, 256, 0, stream>>>(post2 + 2 * stride * 8, nb0, nb1,
                                                       w3t + KNBR * 16 * 8, pre3, nullptr, N, B);
    conv8<16, true, false><<<2 * B4, 256, 0, stream>>>(post2 + 4 * stride * 8, nb0, nb1,
                                                       w3t + 2 * KNBR * 16 * 8, pre3, nullptr, N, B);
    conv8<16, true, true><<<2 * B4, 256, 0, stream>>>(post2 + 6 * stride * 8, nb0, nb1,
                                                      w3t + 3 * KNBR * 16 * 8, pre3, partials, N, B);
    stats_kernel<16><<<dim3(1, 2), 256, 0, stream>>>(partials, B, N, g3, b3, ssb);

    const int bpb = (Ppb + 2047) / 2048;
    const int PB = bpb * bs;
    const int PB4 = ((PB + 3) / 4) * 4;
    pointsum_kernel<<<2 * PB4, 256, 0, stream>>>(pre3, id0, id1, ssb, bsum, N, Ppb, bpb, bs, PB);
    final_kernel<<<1, 64, 0, stream>>>(bsum, Wg, bg, Wr, br, (float*)d_out, bs, 1.0f / Ppb);
}

// Round 8
// 822.623 us; speedup vs baseline: 1.5234x; 1.5234x over previous
//
#include <hip/hip_runtime.h>

// Sparse UNet, fp16 — k-split gather passes over 8-channel L2-resident tables.
//  - s=(bid>>2)&1 stream->XCD partition (validated R6).
//  - every gather pass: 8-ch fp16 table (16B rows, 1.92MB/stream/XCD).
//    conv1: 1 pass; conv2: 2 passes; conv3: 4 passes; later passes accumulate.
//  - k-split: 256 thr = 64 voxels x 4 k-chunks; each thread 7 INDEPENDENT
//    gathers (28 gather VGPRs, no spill) -> 4x memory-level parallelism.
//    Cross-wave reduce via LDS buffer reused from the weight stage.
//  - nt loads for nbr; nt stores for outputs; plain cached gathers.

#define DEVI __device__ __forceinline__

typedef _Float16 h2 __attribute__((ext_vector_type(2)));
typedef unsigned u4 __attribute__((ext_vector_type(4)));
typedef unsigned u2v __attribute__((ext_vector_type(2)));

constexpr int KNBR = 27;

DEVI h2 bch2(unsigned u) { return __builtin_bit_cast(h2, u); }
DEVI unsigned pkh2(float a, float b) {
    h2 v; v.x = (_Float16)a; v.y = (_Float16)b;
    return __builtin_bit_cast(unsigned, v);
}
DEVI float bnr(float x, float sc, float sh) {
    float y = fmaf(x, sc, sh);
    return y > 0.f ? y : 0.f;
}

// ---------------- prep ----------------

// b0: W1 [k][6][16]  -> [k][16][8]
// b1: W2 [k][16][32] -> [h:2][k][32][8]
// b2: W3 [k][32][16] -> [q:4][k][16][8]
// b3: zero bsum
__global__ __launch_bounds__(256)
void prep_weights_kernel(const float* __restrict__ W1, const float* __restrict__ W2,
                         const float* __restrict__ W3,
                         _Float16* __restrict__ w1t, _Float16* __restrict__ w2t,
                         _Float16* __restrict__ w3t,
                         float* __restrict__ bsum, int nb)
{
    const int b = blockIdx.x;
    if (b == 3) {
        for (int i = threadIdx.x; i < nb; i += 256) bsum[i] = 0.f;
        return;
    }
    if (b == 0) {
        for (int i = threadIdx.x; i < KNBR * 16 * 8; i += 256) {
            const int c = i % 8, d = (i / 8) % 16, k = i / 128;
            w1t[i] = (_Float16)((c < 6) ? W1[(k * 6 + c) * 16 + d] : 0.f);
        }
    } else if (b == 1) {
        for (int i = threadIdx.x; i < 2 * KNBR * 32 * 8; i += 256) {
            const int c = i % 8, d = (i / 8) % 32, k = (i / 256) % KNBR, h = i / (256 * KNBR);
            w2t[i] = (_Float16)W2[(k * 16 + h * 8 + c) * 32 + d];
        }
    } else {
        for (int i = threadIdx.x; i < 4 * KNBR * 16 * 8; i += 256) {
            const int c = i % 8, d = (i / 8) % 16, k = (i / 128) % KNBR, q = i / (128 * KNBR);
            w3t[i] = (_Float16)W3[(k * 32 + q * 8 + c) * 16 + d];
        }
    }
}

// fp32 [N][6] -> fp16 [s][(N+1)][8] (pad channels, zero row N)
__global__ __launch_bounds__(256)
void prep_feats_kernel(const float* __restrict__ f0, const float* __restrict__ f1,
                       _Float16* __restrict__ o, int N)
{
    const int s = blockIdx.y;
    const float* __restrict__ f = s ? f1 : f0;
    _Float16* __restrict__ out = o + (size_t)s * (N + 1) * 8;
    const int n = blockIdx.x * 256 + threadIdx.x;
    if (n < N) {
        const float2* r = (const float2*)(f + (size_t)n * 6);
        float2 a = r[0], b = r[1], c = r[2];
        u4 w;
        w.x = pkh2(a.x, a.y);
        w.y = pkh2(b.x, b.y);
        w.z = pkh2(c.x, c.y);
        w.w = 0u;
        ((u4*)out)[n] = w;
    } else if (n == N) {
        ((u4*)out)[n] = (u4){0u, 0u, 0u, 0u};
    }
}

// ---------------- k-split 8-channel gather pass ----------------
// feats: [s][(N+1)][8] phase table; Wt: [27][COUT][8] fp16.
// 256 thr = 64 voxels x 4 k-chunks (7 k each, padded with zero-row gathers).
// outp: [s][(N+1)][COUT] fp16; ACCUM adds prior contents.

template<int COUT, bool ACCUM, bool STATS>
__global__ __launch_bounds__(256)
void conv8k(const _Float16* __restrict__ feats,
            const int* __restrict__ nb0, const int* __restrict__ nb1,
            const _Float16* __restrict__ Wt,
            _Float16* __restrict__ outp,
            float* __restrict__ partials, int N, int B)
{
    constexpr int CPT = COUT / 4;             // channels per combine-thread
    constexpr int REDF = 4 * COUT * 64;       // floats in reduce buffer
    __shared__ __align__(16) float buf[REDF]; // stage1: weights; stage2: reduce

    const int bid = blockIdx.x;
    const int s = (bid >> 2) & 1;
    const int vb = (bid >> 3) * 4 + (bid & 3);
    if (vb >= B) return;
    const int tid = threadIdx.x;

    // load weights (27 rows) + zero pad row 27
    u4* wl = (u4*)buf;
    for (int i = tid; i < 27 * COUT; i += 256) wl[i] = ((const u4*)Wt)[i];
    for (int i = 27 * COUT + tid; i < 28 * COUT; i += 256) wl[i] = (u4){0u, 0u, 0u, 0u};
    __syncthreads();

    const size_t stride = (size_t)N + 1;
    const _Float16* __restrict__ fs = feats + (size_t)s * stride * 8;
    const int* __restrict__ nbr = s ? nb1 : nb0;

    const int lane6 = tid & 63;
    const int kc = tid >> 6;
    const int n = vb * 64 + lane6;
    const bool act = n < N;
    const int k0 = kc * 7;
    const int* nrow = nbr + (size_t)(act ? n : 0) * KNBR;

    // 7 independent gathers (zero-row pad for k>=27 or inactive)
    int ix[7];
    u4 g[7];
    #pragma unroll
    for (int j = 0; j < 7; ++j)
        ix[j] = (act && k0 + j < KNBR) ? __builtin_nontemporal_load(nrow + k0 + j) : N;
    #pragma unroll
    for (int j = 0; j < 7; ++j) g[j] = *(const u4*)(fs + (size_t)ix[j] * 8);

    float acc[COUT];
    #pragma unroll
    for (int d = 0; d < COUT; ++d) acc[d] = 0.f;

    #pragma unroll
    for (int j = 0; j < 7; ++j) {
        #pragma unroll
        for (int d = 0; d < COUT; ++d) {
            const u4 wv = wl[(k0 + j) * COUT + d];
            acc[d] = __builtin_amdgcn_fdot2(bch2(g[j].x), bch2(wv.x), acc[d], false);
            acc[d] = __builtin_amdgcn_fdot2(bch2(g[j].y), bch2(wv.y), acc[d], false);
            acc[d] = __builtin_amdgcn_fdot2(bch2(g[j].z), bch2(wv.z), acc[d], false);
            acc[d] = __builtin_amdgcn_fdot2(bch2(g[j].w), bch2(wv.w), acc[d], false);
        }
    }

    __syncthreads();   // all dots done reading weights -> buf reusable
    // red[kc][c][lane]: lane-stride 4B, conflict-free
    #pragma unroll
    for (int d = 0; d < COUT; ++d) buf[(kc * COUT + d) * 64 + lane6] = acc[d];
    __syncthreads();

    // combine: thread (v = tid&63, cg = tid>>6) handles CPT channels of voxel v
    const int v = tid & 63;
    const int cg = tid >> 6;
    const int nv = vb * 64 + v;
    const bool actv = nv < N;

    float val[CPT];
    #pragma unroll
    for (int j = 0; j < CPT; ++j) {
        const int c = cg * CPT + j;
        val[j] = buf[(0 * COUT + c) * 64 + v] + buf[(1 * COUT + c) * 64 + v]
               + buf[(2 * COUT + c) * 64 + v] + buf[(3 * COUT + c) * 64 + v];
    }

    _Float16* orow = outp + ((size_t)s * stride + nv) * COUT + cg * CPT;
    if constexpr (ACCUM) {
        if (actv) {
            if constexpr (CPT == 8) {
                const u4 p = *(const u4*)orow;
                h2 x;
                x = bch2(p.x); val[0] += (float)x.x; val[1] += (float)x.y;
                x = bch2(p.y); val[2] += (float)x.x; val[3] += (float)x.y;
                x = bch2(p.z); val[4] += (float)x.x; val[5] += (float)x.y;
                x = bch2(p.w); val[6] += (float)x.x; val[7] += (float)x.y;
            } else {
                const u2v p = *(const u2v*)orow;
                h2 x;
                x = bch2(p.x); val[0] += (float)x.x; val[1] += (float)x.y;
                x = bch2(p.y); val[2] += (float)x.x; val[3] += (float)x.y;
            }
        }
    }

    if (actv) {
        if constexpr (CPT == 8) {
            u4 w = {pkh2(val[0], val[1]), pkh2(val[2], val[3]),
                    pkh2(val[4], val[5]), pkh2(val[6], val[7])};
            __builtin_nontemporal_store(w, (u4*)orow);
        } else {
            u2v w = {pkh2(val[0], val[1]), pkh2(val[2], val[3])};
            __builtin_nontemporal_store(w, (u2v*)orow);
        }
    }

    if constexpr (STATS) {
        // wave = 64 voxels (lanes), fixed cg -> shuffle-reduce per channel
        float ts[CPT], tq[CPT];
        #pragma unroll
        for (int j = 0; j < CPT; ++j) {
            const float x = actv ? val[j] : 0.f;
            ts[j] = x; tq[j] = x * x;
        }
        #pragma unroll
        for (int j = 0; j < CPT; ++j) {
            #pragma unroll
            for (int m = 32; m >= 1; m >>= 1) {
                ts[j] += __shfl_xor(ts[j], m);
                tq[j] += __shfl_xor(tq[j], m);
            }
        }
        if (v == 0) {
            float* P = partials + ((size_t)s * B + vb) * 64;
            #pragma unroll
            for (int j = 0; j < CPT; ++j) {
                P[cg * CPT + j] = ts[j];
                P[COUT + cg * CPT + j] = tq[j];
            }
        }
    }
}

// ---------------- BN stats -> scale/shift ----------------

template<int COUT>
__global__ __launch_bounds__(256)
void stats_kernel(const float* __restrict__ partials, int B, int N,
                  const float* __restrict__ g, const float* __restrict__ b,
                  float* __restrict__ ss)
{
    const int s = blockIdx.y;
    const int tid = threadIdx.x;
    const float* P = partials + (size_t)s * B * 64;
    const int q = tid & 63;
    const int ch = tid >> 6;
    float a = 0.f;
    for (int i = ch; i < B; i += 4) a += P[(size_t)i * 64 + q];
    __shared__ float red[256];
    red[tid] = a;
    __syncthreads();
    if (tid < 64) red[tid] = red[tid] + red[64 + tid] + red[128 + tid] + red[192 + tid];
    __syncthreads();
    if (tid < COUT) {
        float sum = red[tid];
        float sq = red[COUT + tid];
        float mean = sum / (float)N;
        float var = sq / (float)N - mean * mean;
        float scl = g[tid] * rsqrtf(var + 1e-4f);
        float sft = b[tid] - mean * scl;
        float* ssp = ss + s * 64;
        ssp[tid] = scl;
        ssp[32 + tid] = sft;
    }
}

// ---------------- apply BN+ReLU, write 8-ch split tables [ph][s][str][8] ----------------

template<int COUT>
__global__ __launch_bounds__(256)
void apply_split_kernel(const _Float16* __restrict__ pre, _Float16* __restrict__ post,
                        const float* __restrict__ ss, int N)
{
    constexpr int CH8 = COUT / 8;
    const int s = blockIdx.y;
    const size_t stride = (size_t)N + 1;
    __shared__ float sc[32], sh[32];
    if (threadIdx.x < COUT) {
        sc[threadIdx.x] = ss[s * 64 + threadIdx.x];
        sh[threadIdx.x] = ss[s * 64 + 32 + threadIdx.x];
    }
    __syncthreads();
    const long long chunks = (long long)stride * CH8;
    const long long i = (long long)blockIdx.x * 256 + threadIdx.x;
    if (i >= chunks) return;
    const int row = (int)(i / CH8);
    const int ph8 = (int)(i % CH8);
    const int cb = ph8 * 8;
    const u4 v = __builtin_nontemporal_load((const u4*)pre + (size_t)s * stride * CH8 + i);
    u4 r;
    {
        h2 x0 = bch2(v.x), x1 = bch2(v.y), x2 = bch2(v.z), x3 = bch2(v.w);
        r.x = pkh2(bnr((float)x0.x, sc[cb + 0], sh[cb + 0]), bnr((float)x0.y, sc[cb + 1], sh[cb + 1]));
        r.y = pkh2(bnr((float)x1.x, sc[cb + 2], sh[cb + 2]), bnr((float)x1.y, sc[cb + 3], sh[cb + 3]));
        r.z = pkh2(bnr((float)x2.x, sc[cb + 4], sh[cb + 4]), bnr((float)x2.y, sc[cb + 5], sh[cb + 5]));
        r.w = pkh2(bnr((float)x3.x, sc[cb + 6], sh[cb + 6]), bnr((float)x3.y, sc[cb + 7], sh[cb + 7]));
    }
    if (row >= N) r = (u4){0u, 0u, 0u, 0u};
    __builtin_nontemporal_store(r, (u4*)post + (size_t)(ph8 * 2 + s) * stride + row);
}

// ---------------- point gather + per-batch channel sums (BN3 inline) ----------------

__global__ __launch_bounds__(256)
void pointsum_kernel(const _Float16* __restrict__ h3,  // [s][(N+1)][16] pre-BN fp16
                     const int* __restrict__ id0, const int* __restrict__ id1,
                     const float* __restrict__ ss, float* __restrict__ bsum,
                     int N, int Ppb, int bpb, int bs, int PB)
{
    const int bid = blockIdx.x;
    const int s = (bid >> 2) & 1;
    const int pb = (bid >> 3) * 4 + (bid & 3);
    if (pb >= PB) return;
    const int batch = pb / bpb;
    const int blk = pb % bpb;

    const _Float16* __restrict__ h = h3 + (size_t)s * (N + 1) * 16;
    const int* __restrict__ ids = s ? id1 : id0;

    const float* ssp = ss + s * 64;
    float sc[16], sh[16];
    #pragma unroll
    for (int c = 0; c < 16; ++c) { sc[c] = ssp[c]; sh[c] = ssp[32 + c]; }

    float acc[16];
    #pragma unroll
    for (int c = 0; c < 16; ++c) acc[c] = 0.f;

    const int* bid_p = ids + (size_t)batch * Ppb;
    const int base = blk * (256 * 8) + threadIdx.x;
    for (int i = 0; i < 8; ++i) {
        int off = base + i * 256;
        if (off < Ppb) {
            int vx = __builtin_nontemporal_load(bid_p + off);
            const u4* r = (const u4*)(h + (size_t)vx * 16);
            u4 a = r[0], b = r[1];
            h2 x;
            x = bch2(a.x); acc[0] += bnr((float)x.x, sc[0], sh[0]);   acc[1] += bnr((float)x.y, sc[1], sh[1]);
            x = bch2(a.y); acc[2] += bnr((float)x.x, sc[2], sh[2]);   acc[3] += bnr((float)x.y, sc[3], sh[3]);
            x = bch2(a.z); acc[4] += bnr((float)x.x, sc[4], sh[4]);   acc[5] += bnr((float)x.y, sc[5], sh[5]);
            x = bch2(a.w); acc[6] += bnr((float)x.x, sc[6], sh[6]);   acc[7] += bnr((float)x.y, sc[7], sh[7]);
            x = bch2(b.x); acc[8] += bnr((float)x.x, sc[8], sh[8]);   acc[9] += bnr((float)x.y, sc[9], sh[9]);
            x = bch2(b.y); acc[10] += bnr((float)x.x, sc[10], sh[10]); acc[11] += bnr((float)x.y, sc[11], sh[11]);
            x = bch2(b.z); acc[12] += bnr((float)x.x, sc[12], sh[12]); acc[13] += bnr((float)x.y, sc[13], sh[13]);
            x = bch2(b.w); acc[14] += bnr((float)x.x, sc[14], sh[14]); acc[15] += bnr((float)x.y, sc[15], sh[15]);
        }
    }

    #pragma unroll
    for (int c = 0; c < 16; ++c) {
        #pragma unroll
        for (int m = 32; m >= 1; m >>= 1) acc[c] += __shfl_xor(acc[c], m);
    }
    __shared__ float sred[4][16];
    const int lane = threadIdx.x & 63, wid = threadIdx.x >> 6;
    if (lane == 0) {
        #pragma unroll
        for (int c = 0; c < 16; ++c) sred[wid][c] = acc[c];
    }
    __syncthreads();
    if (threadIdx.x < 16) {
        float tot = sred[0][threadIdx.x] + sred[1][threadIdx.x] + sred[2][threadIdx.x] + sred[3][threadIdx.x];
        atomicAdd(&bsum[((size_t)s * bs + batch) * 16 + threadIdx.x], tot);
    }
}

// ---------------- head ----------------

__global__ void final_kernel(const float* __restrict__ bsum,
                             const float* __restrict__ Wg, const float* __restrict__ bg,
                             const float* __restrict__ Wr, const float* __restrict__ br,
                             float* __restrict__ out, int bs, float invP)
{
    const int t = threadIdx.x;
    const int total = 4 * bs * 3;
    if (t < total) {
        const int x = t % 3;
        const int b = (t / 3) % bs;
        const int r = t / (3 * bs);
        const int s = r & 1;
        const float* W = (r < 2) ? Wg : Wr;
        const float* bias = (r < 2) ? bg : br;
        const float* m = bsum + ((size_t)s * bs + b) * 16;
        float a = bias[x];
        #pragma unroll
        for (int c = 0; c < 16; ++c) a = fmaf(m[c] * invP, W[c * 3 + x], a);
        out[t] = a;
    }
}

// ---------------- launch ----------------

extern "C" void kernel_launch(void* const* d_in, const int* in_sizes, int n_in,
                              void* d_out, int out_size, void* d_ws, size_t ws_size,
                              hipStream_t stream)
{
    (void)n_in; (void)ws_size;
    const float* vf0 = (const float*)d_in[0];
    const int*   nb0 = (const int*)d_in[1];
    const int*   id0 = (const int*)d_in[2];
    const float* vf1 = (const float*)d_in[3];
    const int*   nb1 = (const int*)d_in[4];
    const int*   id1 = (const int*)d_in[5];
    const float* W1 = (const float*)d_in[7];
    const float* g1 = (const float*)d_in[8];
    const float* b1 = (const float*)d_in[9];
    const float* W2 = (const float*)d_in[10];
    const float* g2 = (const float*)d_in[11];
    const float* b2 = (const float*)d_in[12];
    const float* W3 = (const float*)d_in[13];
    const float* g3 = (const float*)d_in[14];
    const float* b3 = (const float*)d_in[15];
    const float* Wg = (const float*)d_in[16];
    const float* bg = (const float*)d_in[17];
    const float* Wr = (const float*)d_in[18];
    const float* br = (const float*)d_in[19];

    const int N = in_sizes[0] / 6;       // 120000
    const int npts = in_sizes[2];        // bs * P
    const int bs = out_size / 12;        // out = [4, bs, 3]
    const int Ppb = npts / bs;
    const size_t stride = (size_t)N + 1;

    const int B = (N + 63) / 64;         // 64-voxel blocks per stream (k-split)
    const int B4 = ((B + 3) / 4) * 4;

    // Arena (halves), lifetime reuse:
    //  A [64*str]: pre2 accum [s][str][32]
    //  C [64*str]: fin [s][str][8] + pre1 [s][str][16] -> post2 [q:4][s][str][8]
    //  D [32*str]: post1 [h:2][s][str][8]
    //  E [32*str]: pre3 accum [s][str][16]
    _Float16* A   = (_Float16*)d_ws;
    _Float16* C   = A + 64 * stride;
    _Float16* D   = C + 64 * stride;
    _Float16* E   = D + 32 * stride;
    _Float16* w1t = E + 32 * stride;                    // 3456
    _Float16* w2t = w1t + KNBR * 16 * 8;                // 13824
    _Float16* w3t = w2t + 2 * KNBR * 32 * 8;            // 13824
    float* partials = (float*)(w3t + 4 * KNBR * 16 * 8);   // 2*B*64
    float* ssb  = partials + (size_t)2 * B * 64;        // 128
    float* bsum = ssb + 128;                            // 2*bs*16

    _Float16* fin   = C;
    _Float16* pre1  = C + 16 * stride;
    _Float16* post1 = D;            // [h:2][s][str][8]
    _Float16* pre2  = A;            // [s][str][32]
    _Float16* post2 = C;            // [q:4][s][str][8]
    _Float16* pre3  = E;            // [s][str][16]

    prep_feats_kernel<<<dim3((unsigned)((stride + 255) / 256), 2), 256, 0, stream>>>(vf0, vf1, fin, N);
    prep_weights_kernel<<<4, 256, 0, stream>>>(W1, W2, W3, w1t, w2t, w3t, bsum, 2 * bs * 16);

    const int cgrid = 2 * B4;

    // conv1: fin -> pre1 (+stats)
    conv8k<16, false, true><<<cgrid, 256, 0, stream>>>(fin, nb0, nb1, w1t, pre1, partials, N, B);
    stats_kernel<16><<<dim3(1, 2), 256, 0, stream>>>(partials, B, N, g1, b1, ssb);
    apply_split_kernel<16><<<dim3((unsigned)((stride * 2 + 255) / 256), 2), 256, 0, stream>>>(pre1, post1, ssb, N);

    // conv2: two 8-ch passes, second accumulates (+stats)
    conv8k<32, false, false><<<cgrid, 256, 0, stream>>>(post1, nb0, nb1, w2t, pre2, nullptr, N, B);
    conv8k<32, true, true><<<cgrid, 256, 0, stream>>>(post1 + 2 * stride * 8, nb0, nb1,
                                                      w2t + KNBR * 32 * 8, pre2, partials, N, B);
    stats_kernel<32><<<dim3(1, 2), 256, 0, stream>>>(partials, B, N, g2, b2, ssb);
    apply_split_kernel<32><<<dim3((unsigned)((stride * 4 + 255) / 256), 2), 256, 0, stream>>>(pre2, post2, ssb, N);

    // conv3: four 8-ch passes, later ones accumulate, last does stats
    conv8k<16, false, false><<<cgrid, 256, 0, stream>>>(post2, nb0, nb1, w3t, pre3, nullptr, N, B);
    conv8k<16, true, false><<<cgrid, 256, 0, stream>>>(post2 + 2 * stride * 8, nb0, nb1,
                                                       w3t + KNBR * 16 * 8, pre3, nullptr, N, B);
    conv8k<16, true, false><<<cgrid, 256, 0, stream>>>(post2 + 4 * stride * 8, nb0, nb1,
                                                       w3t + 2 * KNBR * 16 * 8, pre3, nullptr, N, B);
    conv8k<16, true, true><<<cgrid, 256, 0, stream>>>(post2 + 6 * stride * 8, nb0, nb1,
                                                      w3t + 3 * KNBR * 16 * 8, pre3, partials, N, B);
    stats_kernel<16><<<dim3(1, 2), 256, 0, stream>>>(partials, B, N, g3, b3, ssb);

    const int bpb = (Ppb + 2047) / 2048;
    const int PB = bpb * bs;
    const int PB4 = ((PB + 3) / 4) * 4;
    pointsum_kernel<<<2 * PB4, 256, 0, stream>>>(pre3, id0, id1, ssb, bsum, N, Ppb, bpb, bs, PB);
    final_kernel<<<1, 64, 0, stream>>>(bsum, Wg, bg, Wr, br, (float*)d_out, bs, 1.0f / Ppb);
}

// Round 9
// 506.537 us; speedup vs baseline: 2.4740x; 1.6240x over previous
//
#include <hip/hip_runtime.h>

// Sparse UNet, fp16 — k-split gather passes over 8-channel L2-resident tables.
//  - s=(bid>>2)&1 stream->XCD partition (validated R6).
//  - every gather pass: 8-ch fp16 table (16B rows, 1.92MB/stream/XCD).
//    conv1: 1 pass; conv2: 2 passes; conv3: 4 passes; later passes accumulate.
//  - k-split: 256 thr = 64 voxels x 4 k-chunks; each thread 7 INDEPENDENT
//    gathers (no spill) -> 4x memory-level parallelism. (R8: conv passes fast.)
//  - R9 fix: two-stage BN-stats reduction (B=1875 rows was reduced by a
//    2-block grid -> 115us latency-bound; now 64x2 blocks stage A + tiny B).

#define DEVI __device__ __forceinline__

typedef _Float16 h2 __attribute__((ext_vector_type(2)));
typedef unsigned u4 __attribute__((ext_vector_type(4)));
typedef unsigned u2v __attribute__((ext_vector_type(2)));

constexpr int KNBR = 27;
constexpr int NSA = 64;    // stage-A blocks per stream

DEVI h2 bch2(unsigned u) { return __builtin_bit_cast(h2, u); }
DEVI unsigned pkh2(float a, float b) {
    h2 v; v.x = (_Float16)a; v.y = (_Float16)b;
    return __builtin_bit_cast(unsigned, v);
}
DEVI float bnr(float x, float sc, float sh) {
    float y = fmaf(x, sc, sh);
    return y > 0.f ? y : 0.f;
}

// ---------------- prep ----------------

__global__ __launch_bounds__(256)
void prep_weights_kernel(const float* __restrict__ W1, const float* __restrict__ W2,
                         const float* __restrict__ W3,
                         _Float16* __restrict__ w1t, _Float16* __restrict__ w2t,
                         _Float16* __restrict__ w3t,
                         float* __restrict__ bsum, int nb)
{
    const int b = blockIdx.x;
    if (b == 3) {
        for (int i = threadIdx.x; i < nb; i += 256) bsum[i] = 0.f;
        return;
    }
    if (b == 0) {
        for (int i = threadIdx.x; i < KNBR * 16 * 8; i += 256) {
            const int c = i % 8, d = (i / 8) % 16, k = i / 128;
            w1t[i] = (_Float16)((c < 6) ? W1[(k * 6 + c) * 16 + d] : 0.f);
        }
    } else if (b == 1) {
        for (int i = threadIdx.x; i < 2 * KNBR * 32 * 8; i += 256) {
            const int c = i % 8, d = (i / 8) % 32, k = (i / 256) % KNBR, h = i / (256 * KNBR);
            w2t[i] = (_Float16)W2[(k * 16 + h * 8 + c) * 32 + d];
        }
    } else {
        for (int i = threadIdx.x; i < 4 * KNBR * 16 * 8; i += 256) {
            const int c = i % 8, d = (i / 8) % 16, k = (i / 128) % KNBR, q = i / (128 * KNBR);
            w3t[i] = (_Float16)W3[(k * 32 + q * 8 + c) * 16 + d];
        }
    }
}

// fp32 [N][6] -> fp16 [s][(N+1)][8] (pad channels, zero row N)
__global__ __launch_bounds__(256)
void prep_feats_kernel(const float* __restrict__ f0, const float* __restrict__ f1,
                       _Float16* __restrict__ o, int N)
{
    const int s = blockIdx.y;
    const float* __restrict__ f = s ? f1 : f0;
    _Float16* __restrict__ out = o + (size_t)s * (N + 1) * 8;
    const int n = blockIdx.x * 256 + threadIdx.x;
    if (n < N) {
        const float2* r = (const float2*)(f + (size_t)n * 6);
        float2 a = r[0], b = r[1], c = r[2];
        u4 w;
        w.x = pkh2(a.x, a.y);
        w.y = pkh2(b.x, b.y);
        w.z = pkh2(c.x, c.y);
        w.w = 0u;
        ((u4*)out)[n] = w;
    } else if (n == N) {
        ((u4*)out)[n] = (u4){0u, 0u, 0u, 0u};
    }
}

// ---------------- k-split 8-channel gather pass ----------------

template<int COUT, bool ACCUM, bool STATS>
__global__ __launch_bounds__(256)
void conv8k(const _Float16* __restrict__ feats,
            const int* __restrict__ nb0, const int* __restrict__ nb1,
            const _Float16* __restrict__ Wt,
            _Float16* __restrict__ outp,
            float* __restrict__ partials, int N, int B)
{
    constexpr int CPT = COUT / 4;
    constexpr int REDF = 4 * COUT * 64;
    __shared__ __align__(16) float buf[REDF];

    const int bid = blockIdx.x;
    const int s = (bid >> 2) & 1;
    const int vb = (bid >> 3) * 4 + (bid & 3);
    if (vb >= B) return;
    const int tid = threadIdx.x;

    u4* wl = (u4*)buf;
    for (int i = tid; i < 27 * COUT; i += 256) wl[i] = ((const u4*)Wt)[i];
    for (int i = 27 * COUT + tid; i < 28 * COUT; i += 256) wl[i] = (u4){0u, 0u, 0u, 0u};
    __syncthreads();

    const size_t stride = (size_t)N + 1;
    const _Float16* __restrict__ fs = feats + (size_t)s * stride * 8;
    const int* __restrict__ nbr = s ? nb1 : nb0;

    const int lane6 = tid & 63;
    const int kc = tid >> 6;
    const int n = vb * 64 + lane6;
    const bool act = n < N;
    const int k0 = kc * 7;
    const int* nrow = nbr + (size_t)(act ? n : 0) * KNBR;

    int ix[7];
    u4 g[7];
    #pragma unroll
    for (int j = 0; j < 7; ++j)
        ix[j] = (act && k0 + j < KNBR) ? __builtin_nontemporal_load(nrow + k0 + j) : N;
    #pragma unroll
    for (int j = 0; j < 7; ++j) g[j] = *(const u4*)(fs + (size_t)ix[j] * 8);

    float acc[COUT];
    #pragma unroll
    for (int d = 0; d < COUT; ++d) acc[d] = 0.f;

    #pragma unroll
    for (int j = 0; j < 7; ++j) {
        #pragma unroll
        for (int d = 0; d < COUT; ++d) {
            const u4 wv = wl[(k0 + j) * COUT + d];
            acc[d] = __builtin_amdgcn_fdot2(bch2(g[j].x), bch2(wv.x), acc[d], false);
            acc[d] = __builtin_amdgcn_fdot2(bch2(g[j].y), bch2(wv.y), acc[d], false);
            acc[d] = __builtin_amdgcn_fdot2(bch2(g[j].z), bch2(wv.z), acc[d], false);
            acc[d] = __builtin_amdgcn_fdot2(bch2(g[j].w), bch2(wv.w), acc[d], false);
        }
    }

    __syncthreads();
    #pragma unroll
    for (int d = 0; d < COUT; ++d) buf[(kc * COUT + d) * 64 + lane6] = acc[d];
    __syncthreads();

    const int v = tid & 63;
    const int cg = tid >> 6;
    const int nv = vb * 64 + v;
    const bool actv = nv < N;

    float val[CPT];
    #pragma unroll
    for (int j = 0; j < CPT; ++j) {
        const int c = cg * CPT + j;
        val[j] = buf[(0 * COUT + c) * 64 + v] + buf[(1 * COUT + c) * 64 + v]
               + buf[(2 * COUT + c) * 64 + v] + buf[(3 * COUT + c) * 64 + v];
    }

    _Float16* orow = outp + ((size_t)s * stride + nv) * COUT + cg * CPT;
    if constexpr (ACCUM) {
        if (actv) {
            if constexpr (CPT == 8) {
                const u4 p = *(const u4*)orow;
                h2 x;
                x = bch2(p.x); val[0] += (float)x.x; val[1] += (float)x.y;
                x = bch2(p.y); val[2] += (float)x.x; val[3] += (float)x.y;
                x = bch2(p.z); val[4] += (float)x.x; val[5] += (float)x.y;
                x = bch2(p.w); val[6] += (float)x.x; val[7] += (float)x.y;
            } else {
                const u2v p = *(const u2v*)orow;
                h2 x;
                x = bch2(p.x); val[0] += (float)x.x; val[1] += (float)x.y;
                x = bch2(p.y); val[2] += (float)x.x; val[3] += (float)x.y;
            }
        }
    }

    if (actv) {
        if constexpr (CPT == 8) {
            u4 w = {pkh2(val[0], val[1]), pkh2(val[2], val[3]),
                    pkh2(val[4], val[5]), pkh2(val[6], val[7])};
            __builtin_nontemporal_store(w, (u4*)orow);
        } else {
            u2v w = {pkh2(val[0], val[1]), pkh2(val[2], val[3])};
            __builtin_nontemporal_store(w, (u2v*)orow);
        }
    }

    if constexpr (STATS) {
        float ts[CPT], tq[CPT];
        #pragma unroll
        for (int j = 0; j < CPT; ++j) {
            const float x = actv ? val[j] : 0.f;
            ts[j] = x; tq[j] = x * x;
        }
        #pragma unroll
        for (int j = 0; j < CPT; ++j) {
            #pragma unroll
            for (int m = 32; m >= 1; m >>= 1) {
                ts[j] += __shfl_xor(ts[j], m);
                tq[j] += __shfl_xor(tq[j], m);
            }
        }
        if (v == 0) {
            float* P = partials + ((size_t)s * B + vb) * 64;
            #pragma unroll
            for (int j = 0; j < CPT; ++j) {
                P[cg * CPT + j] = ts[j];
                P[COUT + cg * CPT + j] = tq[j];
            }
        }
    }
}

// ---------------- stats stage A: B rows -> NSA rows per stream ----------------

__global__ __launch_bounds__(256)
void stats_a_kernel(const float* __restrict__ partials, float* __restrict__ mid,
                    int B)
{
    const int s = blockIdx.y;
    const int blk = blockIdx.x;         // 0..NSA-1
    const int tid = threadIdx.x;
    const int q = tid & 63;
    const int rr = tid >> 6;
    const int chunk = (B + NSA - 1) / NSA;
    const int start = blk * chunk;
    const int end = min(B, start + chunk);
    const float* P = partials + (size_t)s * B * 64;
    float a = 0.f;
    for (int i = start + rr; i < end; i += 4) a += P[(size_t)i * 64 + q];
    __shared__ float red[256];
    red[tid] = a;
    __syncthreads();
    if (tid < 64) {
        float tot = red[tid] + red[64 + tid] + red[128 + tid] + red[192 + tid];
        mid[((size_t)s * NSA + blk) * 64 + tid] = tot;
    }
}

// ---------------- stats stage B: NSA rows -> scale/shift ----------------

template<int COUT>
__global__ __launch_bounds__(256)
void stats_kernel(const float* __restrict__ mid, int N,
                  const float* __restrict__ g, const float* __restrict__ b,
                  float* __restrict__ ss)
{
    const int s = blockIdx.y;
    const int tid = threadIdx.x;
    const float* P = mid + (size_t)s * NSA * 64;
    const int q = tid & 63;
    const int ch = tid >> 6;
    float a = 0.f;
    for (int i = ch; i < NSA; i += 4) a += P[(size_t)i * 64 + q];
    __shared__ float red[256];
    red[tid] = a;
    __syncthreads();
    if (tid < 64) red[tid] = red[tid] + red[64 + tid] + red[128 + tid] + red[192 + tid];
    __syncthreads();
    if (tid < COUT) {
        float sum = red[tid];
        float sq = red[COUT + tid];
        float mean = sum / (float)N;
        float var = sq / (float)N - mean * mean;
        float scl = g[tid] * rsqrtf(var + 1e-4f);
        float sft = b[tid] - mean * scl;
        float* ssp = ss + s * 64;
        ssp[tid] = scl;
        ssp[32 + tid] = sft;
    }
}

// ---------------- apply BN+ReLU, write 8-ch split tables [ph][s][str][8] ----------------

template<int COUT>
__global__ __launch_bounds__(256)
void apply_split_kernel(const _Float16* __restrict__ pre, _Float16* __restrict__ post,
                        const float* __restrict__ ss, int N)
{
    constexpr int CH8 = COUT / 8;
    const int s = blockIdx.y;
    const size_t stride = (size_t)N + 1;
    __shared__ float sc[32], sh[32];
    if (threadIdx.x < COUT) {
        sc[threadIdx.x] = ss[s * 64 + threadIdx.x];
        sh[threadIdx.x] = ss[s * 64 + 32 + threadIdx.x];
    }
    __syncthreads();
    const long long chunks = (long long)stride * CH8;
    const long long i = (long long)blockIdx.x * 256 + threadIdx.x;
    if (i >= chunks) return;
    const int row = (int)(i / CH8);
    const int ph8 = (int)(i % CH8);
    const int cb = ph8 * 8;
    const u4 v = __builtin_nontemporal_load((const u4*)pre + (size_t)s * stride * CH8 + i);
    u4 r;
    {
        h2 x0 = bch2(v.x), x1 = bch2(v.y), x2 = bch2(v.z), x3 = bch2(v.w);
        r.x = pkh2(bnr((float)x0.x, sc[cb + 0], sh[cb + 0]), bnr((float)x0.y, sc[cb + 1], sh[cb + 1]));
        r.y = pkh2(bnr((float)x1.x, sc[cb + 2], sh[cb + 2]), bnr((float)x1.y, sc[cb + 3], sh[cb + 3]));
        r.z = pkh2(bnr((float)x2.x, sc[cb + 4], sh[cb + 4]), bnr((float)x2.y, sc[cb + 5], sh[cb + 5]));
        r.w = pkh2(bnr((float)x3.x, sc[cb + 6], sh[cb + 6]), bnr((float)x3.y, sc[cb + 7], sh[cb + 7]));
    }
    if (row >= N) r = (u4){0u, 0u, 0u, 0u};
    __builtin_nontemporal_store(r, (u4*)post + (size_t)(ph8 * 2 + s) * stride + row);
}

// ---------------- point gather + per-batch channel sums (BN3 inline) ----------------

__global__ __launch_bounds__(256)
void pointsum_kernel(const _Float16* __restrict__ h3,
                     const int* __restrict__ id0, const int* __restrict__ id1,
                     const float* __restrict__ ss, float* __restrict__ bsum,
                     int N, int Ppb, int bpb, int bs, int PB)
{
    const int bid = blockIdx.x;
    const int s = (bid >> 2) & 1;
    const int pb = (bid >> 3) * 4 + (bid & 3);
    if (pb >= PB) return;
    const int batch = pb / bpb;
    const int blk = pb % bpb;

    const _Float16* __restrict__ h = h3 + (size_t)s * (N + 1) * 16;
    const int* __restrict__ ids = s ? id1 : id0;

    const float* ssp = ss + s * 64;
    float sc[16], sh[16];
    #pragma unroll
    for (int c = 0; c < 16; ++c) { sc[c] = ssp[c]; sh[c] = ssp[32 + c]; }

    float acc[16];
    #pragma unroll
    for (int c = 0; c < 16; ++c) acc[c] = 0.f;

    const int* bid_p = ids + (size_t)batch * Ppb;
    const int base = blk * (256 * 8) + threadIdx.x;
    for (int i = 0; i < 8; ++i) {
        int off = base + i * 256;
        if (off < Ppb) {
            int vx = __builtin_nontemporal_load(bid_p + off);
            const u4* r = (const u4*)(h + (size_t)vx * 16);
            u4 a = r[0], b = r[1];
            h2 x;
            x = bch2(a.x); acc[0] += bnr((float)x.x, sc[0], sh[0]);   acc[1] += bnr((float)x.y, sc[1], sh[1]);
            x = bch2(a.y); acc[2] += bnr((float)x.x, sc[2], sh[2]);   acc[3] += bnr((float)x.y, sc[3], sh[3]);
            x = bch2(a.z); acc[4] += bnr((float)x.x, sc[4], sh[4]);   acc[5] += bnr((float)x.y, sc[5], sh[5]);
            x = bch2(a.w); acc[6] += bnr((float)x.x, sc[6], sh[6]);   acc[7] += bnr((float)x.y, sc[7], sh[7]);
            x = bch2(b.x); acc[8] += bnr((float)x.x, sc[8], sh[8]);   acc[9] += bnr((float)x.y, sc[9], sh[9]);
            x = bch2(b.y); acc[10] += bnr((float)x.x, sc[10], sh[10]); acc[11] += bnr((float)x.y, sc[11], sh[11]);
            x = bch2(b.z); acc[12] += bnr((float)x.x, sc[12], sh[12]); acc[13] += bnr((float)x.y, sc[13], sh[13]);
            x = bch2(b.w); acc[14] += bnr((float)x.x, sc[14], sh[14]); acc[15] += bnr((float)x.y, sc[15], sh[15]);
        }
    }

    #pragma unroll
    for (int c = 0; c < 16; ++c) {
        #pragma unroll
        for (int m = 32; m >= 1; m >>= 1) acc[c] += __shfl_xor(acc[c], m);
    }
    __shared__ float sred[4][16];
    const int lane = threadIdx.x & 63, wid = threadIdx.x >> 6;
    if (lane == 0) {
        #pragma unroll
        for (int c = 0; c < 16; ++c) sred[wid][c] = acc[c];
    }
    __syncthreads();
    if (threadIdx.x < 16) {
        float tot = sred[0][threadIdx.x] + sred[1][threadIdx.x] + sred[2][threadIdx.x] + sred[3][threadIdx.x];
        atomicAdd(&bsum[((size_t)s * bs + batch) * 16 + threadIdx.x], tot);
    }
}

// ---------------- head ----------------

__global__ void final_kernel(const float* __restrict__ bsum,
                             const float* __restrict__ Wg, const float* __restrict__ bg,
                             const float* __restrict__ Wr, const float* __restrict__ br,
                             float* __restrict__ out, int bs, float invP)
{
    const int t = threadIdx.x;
    const int total = 4 * bs * 3;
    if (t < total) {
        const int x = t % 3;
        const int b = (t / 3) % bs;
        const int r = t / (3 * bs);
        const int s = r & 1;
        const float* W = (r < 2) ? Wg : Wr;
        const float* bias = (r < 2) ? bg : br;
        const float* m = bsum + ((size_t)s * bs + b) * 16;
        float a = bias[x];
        #pragma unroll
        for (int c = 0; c < 16; ++c) a = fmaf(m[c] * invP, W[c * 3 + x], a);
        out[t] = a;
    }
}

// ---------------- launch ----------------

extern "C" void kernel_launch(void* const* d_in, const int* in_sizes, int n_in,
                              void* d_out, int out_size, void* d_ws, size_t ws_size,
                              hipStream_t stream)
{
    (void)n_in; (void)ws_size;
    const float* vf0 = (const float*)d_in[0];
    const int*   nb0 = (const int*)d_in[1];
    const int*   id0 = (const int*)d_in[2];
    const float* vf1 = (const float*)d_in[3];
    const int*   nb1 = (const int*)d_in[4];
    const int*   id1 = (const int*)d_in[5];
    const float* W1 = (const float*)d_in[7];
    const float* g1 = (const float*)d_in[8];
    const float* b1 = (const float*)d_in[9];
    const float* W2 = (const float*)d_in[10];
    const float* g2 = (const float*)d_in[11];
    const float* b2 = (const float*)d_in[12];
    const float* W3 = (const float*)d_in[13];
    const float* g3 = (const float*)d_in[14];
    const float* b3 = (const float*)d_in[15];
    const float* Wg = (const float*)d_in[16];
    const float* bg = (const float*)d_in[17];
    const float* Wr = (const float*)d_in[18];
    const float* br = (const float*)d_in[19];

    const int N = in_sizes[0] / 6;
    const int npts = in_sizes[2];
    const int bs = out_size / 12;
    const int Ppb = npts / bs;
    const size_t stride = (size_t)N + 1;

    const int B = (N + 63) / 64;
    const int B4 = ((B + 3) / 4) * 4;

    _Float16* A   = (_Float16*)d_ws;
    _Float16* C   = A + 64 * stride;
    _Float16* D   = C + 64 * stride;
    _Float16* E   = D + 32 * stride;
    _Float16* w1t = E + 32 * stride;
    _Float16* w2t = w1t + KNBR * 16 * 8;
    _Float16* w3t = w2t + 2 * KNBR * 32 * 8;
    float* partials = (float*)(w3t + 4 * KNBR * 16 * 8);   // 2*B*64
    float* mid  = partials + (size_t)2 * B * 64;        // 2*NSA*64
    float* ssb  = mid + 2 * NSA * 64;                   // 128
    float* bsum = ssb + 128;                            // 2*bs*16

    _Float16* fin   = C;
    _Float16* pre1  = C + 16 * stride;
    _Float16* post1 = D;
    _Float16* pre2  = A;
    _Float16* post2 = C;
    _Float16* pre3  = E;

    prep_feats_kernel<<<dim3((unsigned)((stride + 255) / 256), 2), 256, 0, stream>>>(vf0, vf1, fin, N);
    prep_weights_kernel<<<4, 256, 0, stream>>>(W1, W2, W3, w1t, w2t, w3t, bsum, 2 * bs * 16);

    const int cgrid = 2 * B4;

    // conv1: fin -> pre1 (+stats)
    conv8k<16, false, true><<<cgrid, 256, 0, stream>>>(fin, nb0, nb1, w1t, pre1, partials, N, B);
    stats_a_kernel<<<dim3(NSA, 2), 256, 0, stream>>>(partials, mid, B);
    stats_kernel<16><<<dim3(1, 2), 256, 0, stream>>>(mid, N, g1, b1, ssb);
    apply_split_kernel<16><<<dim3((unsigned)((stride * 2 + 255) / 256), 2), 256, 0, stream>>>(pre1, post1, ssb, N);

    // conv2: two 8-ch passes, second accumulates (+stats)
    conv8k<32, false, false><<<cgrid, 256, 0, stream>>>(post1, nb0, nb1, w2t, pre2, nullptr, N, B);
    conv8k<32, true, true><<<cgrid, 256, 0, stream>>>(post1 + 2 * stride * 8, nb0, nb1,
                                                      w2t + KNBR * 32 * 8, pre2, partials, N, B);
    stats_a_kernel<<<dim3(NSA, 2), 256, 0, stream>>>(partials, mid, B);
    stats_kernel<32><<<dim3(1, 2), 256, 0, stream>>>(mid, N, g2, b2, ssb);
    apply_split_kernel<32><<<dim3((unsigned)((stride * 4 + 255) / 256), 2), 256, 0, stream>>>(pre2, post2, ssb, N);

    // conv3: four 8-ch passes, later ones accumulate, last does stats
    conv8k<16, false, false><<<cgrid, 256, 0, stream>>>(post2, nb0, nb1, w3t, pre3, nullptr, N, B);
    conv8k<16, true, false><<<cgrid, 256, 0, stream>>>(post2 + 2 * stride * 8, nb0, nb1,
                                                       w3t + KNBR * 16 * 8, pre3, nullptr, N, B);
    conv8k<16, true, false><<<cgrid, 256, 0, stream>>>(post2 + 4 * stride * 8, nb0, nb1,
                                                       w3t + 2 * KNBR * 16 * 8, pre3, nullptr, N, B);
    conv8k<16, true, true><<<cgrid, 256, 0, stream>>>(post2 + 6 * stride * 8, nb0, nb1,
                                                      w3t + 3 * KNBR * 16 * 8, pre3, partials, N, B);
    stats_a_kernel<<<dim3(NSA, 2), 256, 0, stream>>>(partials, mid, B);
    stats_kernel<16><<<dim3(1, 2), 256, 0, stream>>>(mid, N, g3, b3, ssb);

    const int bpb = (Ppb + 2047) / 2048;
    const int PB = bpb * bs;
    const int PB4 = ((PB + 3) / 4) * 4;
    pointsum_kernel<<<2 * PB4, 256, 0, stream>>>(pre3, id0, id1, ssb, bsum, N, Ppb, bpb, bs, PB);
    final_kernel<<<1, 64, 0, stream>>>(bsum, Wg, bg, Wr, br, (float*)d_out, bs, 1.0f / Ppb);
}

// Round 10
// 390.258 us; speedup vs baseline: 3.2112x; 1.2980x over previous
//
#include <hip/hip_runtime.h>

// Sparse UNet, fp16 — k-split gather passes, in-wave reduce-scatter (R10).
//  - s=(bid>>2)&1 stream->XCD partition; 8-ch (16B row) phase tables
//    (1.92MB/stream/XCD -> ~100% L2 hit, validated R9: FETCH ~= nbr only).
//  - thread map: lane = 4*vx + kc (4 k-chunks of a voxel adjacent in wave).
//    k-reduce = 2-step shfl_xor reduce-scatter (static reg indexing, no LDS
//    buffer, no mid-kernel barriers). Lane ends with CPT=COUT/4 channels at
//    c0 = (kc&1)*(COUT/2) + (kc>>1)*CPT.
//  - LDS: weights only, per-chunk padded (banks 0/4/8/12 -> conflict-free).
//  - conv1: 1 pass; conv2: 2 passes; conv3: 4 passes; later passes accumulate.

#define DEVI __device__ __forceinline__

typedef _Float16 h2 __attribute__((ext_vector_type(2)));
typedef unsigned u4 __attribute__((ext_vector_type(4)));
typedef unsigned u2v __attribute__((ext_vector_type(2)));

constexpr int KNBR = 27;
constexpr int NSA = 64;    // stats stage-A blocks per stream

DEVI h2 bch2(unsigned u) { return __builtin_bit_cast(h2, u); }
DEVI unsigned pkh2(float a, float b) {
    h2 v; v.x = (_Float16)a; v.y = (_Float16)b;
    return __builtin_bit_cast(unsigned, v);
}
DEVI float bnr(float x, float sc, float sh) {
    float y = fmaf(x, sc, sh);
    return y > 0.f ? y : 0.f;
}

// ---------------- prep ----------------

__global__ __launch_bounds__(256)
void prep_weights_kernel(const float* __restrict__ W1, const float* __restrict__ W2,
                         const float* __restrict__ W3,
                         _Float16* __restrict__ w1t, _Float16* __restrict__ w2t,
                         _Float16* __restrict__ w3t,
                         float* __restrict__ bsum, int nb)
{
    const int b = blockIdx.x;
    if (b == 3) {
        for (int i = threadIdx.x; i < nb; i += 256) bsum[i] = 0.f;
        return;
    }
    if (b == 0) {
        for (int i = threadIdx.x; i < KNBR * 16 * 8; i += 256) {
            const int c = i % 8, d = (i / 8) % 16, k = i / 128;
            w1t[i] = (_Float16)((c < 6) ? W1[(k * 6 + c) * 16 + d] : 0.f);
        }
    } else if (b == 1) {
        for (int i = threadIdx.x; i < 2 * KNBR * 32 * 8; i += 256) {
            const int c = i % 8, d = (i / 8) % 32, k = (i / 256) % KNBR, h = i / (256 * KNBR);
            w2t[i] = (_Float16)W2[(k * 16 + h * 8 + c) * 32 + d];
        }
    } else {
        for (int i = threadIdx.x; i < 4 * KNBR * 16 * 8; i += 256) {
            const int c = i % 8, d = (i / 8) % 16, k = (i / 128) % KNBR, q = i / (128 * KNBR);
            w3t[i] = (_Float16)W3[(k * 32 + q * 8 + c) * 16 + d];
        }
    }
}

// fp32 [N][6] -> fp16 [s][(N+1)][8] (pad channels, zero row N)
__global__ __launch_bounds__(256)
void prep_feats_kernel(const float* __restrict__ f0, const float* __restrict__ f1,
                       _Float16* __restrict__ o, int N)
{
    const int s = blockIdx.y;
    const float* __restrict__ f = s ? f1 : f0;
    _Float16* __restrict__ out = o + (size_t)s * (N + 1) * 8;
    const int n = blockIdx.x * 256 + threadIdx.x;
    if (n < N) {
        const float2* r = (const float2*)(f + (size_t)n * 6);
        float2 a = r[0], b = r[1], c = r[2];
        u4 w;
        w.x = pkh2(a.x, a.y);
        w.y = pkh2(b.x, b.y);
        w.z = pkh2(c.x, c.y);
        w.w = 0u;
        ((u4*)out)[n] = w;
    } else if (n == N) {
        ((u4*)out)[n] = (u4){0u, 0u, 0u, 0u};
    }
}

// ---------------- k-split 8-channel gather pass, in-wave reduce-scatter ----------------
// feats: [s][(N+1)][8]; Wt: [27][COUT][8] fp16; outp: [s][(N+1)][COUT].
// 256 thr = 64 voxels x 4 k-chunks, lane = 4*vx + kc.

template<int COUT, bool ACCUM, bool STATS>
__global__ __launch_bounds__(256)
void conv8s(const _Float16* __restrict__ feats,
            const int* __restrict__ nb0, const int* __restrict__ nb1,
            const _Float16* __restrict__ Wt,
            _Float16* __restrict__ outp,
            float* __restrict__ partials, int N, int B)
{
    constexpr int CPT = COUT / 4;
    constexpr int WPAD = 7 * COUT + 1;     // u4 per k-chunk (+1 pad -> bank shift 4)
    __shared__ __align__(16) _Float16 wlraw[4 * WPAD * 8];
    __shared__ float sred[4][64];

    const int bid = blockIdx.x;
    const int s = (bid >> 2) & 1;
    const int vb = (bid >> 3) * 4 + (bid & 3);
    if (vb >= B) return;
    const int tid = threadIdx.x;

    // stage weights into chunked-padded layout; k=27 row zeroed
    u4* wl = (u4*)wlraw;
    for (int i = tid; i < 28 * COUT; i += 256) {
        const int k = i / COUT, d = i % COUT;
        const u4 v = (k < 27) ? ((const u4*)Wt)[i] : (u4){0u, 0u, 0u, 0u};
        wl[(k / 7) * WPAD + (k % 7) * COUT + d] = v;
    }
    __syncthreads();

    const size_t stride = (size_t)N + 1;
    const _Float16* __restrict__ fs = feats + (size_t)s * stride * 8;
    const int* __restrict__ nbr = s ? nb1 : nb0;

    const int vx = tid >> 2;               // 0..63
    const int kc = tid & 3;
    const int n = vb * 64 + vx;
    const bool act = n < N;
    const int k0 = kc * 7;
    const int* nrow = nbr + (size_t)(act ? n : 0) * KNBR;

    int ix[7];
    u4 g[7];
    #pragma unroll
    for (int j = 0; j < 7; ++j)
        ix[j] = (act && k0 + j < KNBR) ? __builtin_nontemporal_load(nrow + k0 + j) : N;
    #pragma unroll
    for (int j = 0; j < 7; ++j) g[j] = *(const u4*)(fs + (size_t)ix[j] * 8);

    const u4* wp = wl + kc * WPAD;

    float acc[COUT];
    #pragma unroll
    for (int d = 0; d < COUT; ++d) acc[d] = 0.f;

    #pragma unroll
    for (int j = 0; j < 7; ++j) {
        #pragma unroll
        for (int d = 0; d < COUT; ++d) {
            const u4 wv = wp[j * COUT + d];
            acc[d] = __builtin_amdgcn_fdot2(bch2(g[j].x), bch2(wv.x), acc[d], false);
            acc[d] = __builtin_amdgcn_fdot2(bch2(g[j].y), bch2(wv.y), acc[d], false);
            acc[d] = __builtin_amdgcn_fdot2(bch2(g[j].z), bch2(wv.z), acc[d], false);
            acc[d] = __builtin_amdgcn_fdot2(bch2(g[j].w), bch2(wv.w), acc[d], false);
        }
    }

    // reduce-scatter across the 4 kc lanes (static reg indexing)
    // step 1: xor 1, keep half selected by kc&1
    float r1[COUT / 2];
    #pragma unroll
    for (int j = 0; j < COUT / 2; ++j) {
        const float lo = acc[j], up = acc[j + COUT / 2];
        const float olo = __shfl_xor(lo, 1), oup = __shfl_xor(up, 1);
        r1[j] = (kc & 1) ? (up + oup) : (lo + olo);
    }
    // step 2: xor 2, keep quarter selected by kc>>1
    float val[CPT];
    #pragma unroll
    for (int j = 0; j < CPT; ++j) {
        const float lo = r1[j], up = r1[j + CPT];
        const float olo = __shfl_xor(lo, 2), oup = __shfl_xor(up, 2);
        val[j] = (kc >> 1) ? (up + oup) : (lo + olo);
    }
    const int c0 = (kc & 1) * (COUT / 2) + (kc >> 1) * CPT;

    _Float16* orow = outp + ((size_t)s * stride + n) * COUT + c0;
    if constexpr (ACCUM) {
        if (act) {
            if constexpr (CPT == 8) {
                const u4 p = *(const u4*)orow;
                h2 x;
                x = bch2(p.x); val[0] += (float)x.x; val[1] += (float)x.y;
                x = bch2(p.y); val[2] += (float)x.x; val[3] += (float)x.y;
                x = bch2(p.z); val[4] += (float)x.x; val[5] += (float)x.y;
                x = bch2(p.w); val[6] += (float)x.x; val[7] += (float)x.y;
            } else {
                const u2v p = *(const u2v*)orow;
                h2 x;
                x = bch2(p.x); val[0] += (float)x.x; val[1] += (float)x.y;
                x = bch2(p.y); val[2] += (float)x.x; val[3] += (float)x.y;
            }
        }
    }

    if (act) {
        if constexpr (CPT == 8) {
            u4 w = {pkh2(val[0], val[1]), pkh2(val[2], val[3]),
                    pkh2(val[4], val[5]), pkh2(val[6], val[7])};
            __builtin_nontemporal_store(w, (u4*)orow);
        } else {
            u2v w = {pkh2(val[0], val[1]), pkh2(val[2], val[3])};
            __builtin_nontemporal_store(w, (u2v*)orow);
        }
    }

    if constexpr (STATS) {
        float ts[CPT], tq[CPT];
        #pragma unroll
        for (int j = 0; j < CPT; ++j) {
            const float x = act ? val[j] : 0.f;
            ts[j] = x; tq[j] = x * x;
        }
        // sum over the 16 voxels in this wave (lane stride 4)
        #pragma unroll
        for (int j = 0; j < CPT; ++j) {
            #pragma unroll
            for (int m = 4; m <= 32; m <<= 1) {
                ts[j] += __shfl_xor(ts[j], m);
                tq[j] += __shfl_xor(tq[j], m);
            }
        }
        const int w = tid >> 6;
        if ((tid & 63) < 4) {
            #pragma unroll
            for (int j = 0; j < CPT; ++j) {
                sred[w][c0 + j] = ts[j];
                sred[w][COUT + c0 + j] = tq[j];
            }
        }
        __syncthreads();
        if (tid < 2 * COUT) {
            float tot = sred[0][tid] + sred[1][tid] + sred[2][tid] + sred[3][tid];
            partials[((size_t)s * B + vb) * 64 + tid] = tot;
        }
    }
}

// ---------------- stats stage A: B rows -> NSA rows per stream ----------------

__global__ __launch_bounds__(256)
void stats_a_kernel(const float* __restrict__ partials, float* __restrict__ mid,
                    int B)
{
    const int s = blockIdx.y;
    const int blk = blockIdx.x;
    const int tid = threadIdx.x;
    const int q = tid & 63;
    const int rr = tid >> 6;
    const int chunk = (B + NSA - 1) / NSA;
    const int start = blk * chunk;
    const int end = min(B, start + chunk);
    const float* P = partials + (size_t)s * B * 64;
    float a = 0.f;
    for (int i = start + rr; i < end; i += 4) a += P[(size_t)i * 64 + q];
    __shared__ float red[256];
    red[tid] = a;
    __syncthreads();
    if (tid < 64) {
        float tot = red[tid] + red[64 + tid] + red[128 + tid] + red[192 + tid];
        mid[((size_t)s * NSA + blk) * 64 + tid] = tot;
    }
}

// ---------------- stats stage B: NSA rows -> scale/shift ----------------

template<int COUT>
__global__ __launch_bounds__(256)
void stats_kernel(const float* __restrict__ mid, int N,
                  const float* __restrict__ g, const float* __restrict__ b,
                  float* __restrict__ ss)
{
    const int s = blockIdx.y;
    const int tid = threadIdx.x;
    const float* P = mid + (size_t)s * NSA * 64;
    const int q = tid & 63;
    const int ch = tid >> 6;
    float a = 0.f;
    for (int i = ch; i < NSA; i += 4) a += P[(size_t)i * 64 + q];
    __shared__ float red[256];
    red[tid] = a;
    __syncthreads();
    if (tid < 64) red[tid] = red[tid] + red[64 + tid] + red[128 + tid] + red[192 + tid];
    __syncthreads();
    if (tid < COUT) {
        float sum = red[tid];
        float sq = red[COUT + tid];
        float mean = sum / (float)N;
        float var = sq / (float)N - mean * mean;
        float scl = g[tid] * rsqrtf(var + 1e-4f);
        float sft = b[tid] - mean * scl;
        float* ssp = ss + s * 64;
        ssp[tid] = scl;
        ssp[32 + tid] = sft;
    }
}

// ---------------- apply BN+ReLU, write 8-ch split tables [ph][s][str][8] ----------------

template<int COUT>
__global__ __launch_bounds__(256)
void apply_split_kernel(const _Float16* __restrict__ pre, _Float16* __restrict__ post,
                        const float* __restrict__ ss, int N)
{
    constexpr int CH8 = COUT / 8;
    const int s = blockIdx.y;
    const size_t stride = (size_t)N + 1;
    __shared__ float sc[32], sh[32];
    if (threadIdx.x < COUT) {
        sc[threadIdx.x] = ss[s * 64 + threadIdx.x];
        sh[threadIdx.x] = ss[s * 64 + 32 + threadIdx.x];
    }
    __syncthreads();
    const long long chunks = (long long)stride * CH8;
    const long long i = (long long)blockIdx.x * 256 + threadIdx.x;
    if (i >= chunks) return;
    const int row = (int)(i / CH8);
    const int ph8 = (int)(i % CH8);
    const int cb = ph8 * 8;
    const u4 v = __builtin_nontemporal_load((const u4*)pre + (size_t)s * stride * CH8 + i);
    u4 r;
    {
        h2 x0 = bch2(v.x), x1 = bch2(v.y), x2 = bch2(v.z), x3 = bch2(v.w);
        r.x = pkh2(bnr((float)x0.x, sc[cb + 0], sh[cb + 0]), bnr((float)x0.y, sc[cb + 1], sh[cb + 1]));
        r.y = pkh2(bnr((float)x1.x, sc[cb + 2], sh[cb + 2]), bnr((float)x1.y, sc[cb + 3], sh[cb + 3]));
        r.z = pkh2(bnr((float)x2.x, sc[cb + 4], sh[cb + 4]), bnr((float)x2.y, sc[cb + 5], sh[cb + 5]));
        r.w = pkh2(bnr((float)x3.x, sc[cb + 6], sh[cb + 6]), bnr((float)x3.y, sc[cb + 7], sh[cb + 7]));
    }
    if (row >= N) r = (u4){0u, 0u, 0u, 0u};
    __builtin_nontemporal_store(r, (u4*)post + (size_t)(ph8 * 2 + s) * stride + row);
}

// ---------------- point gather + per-batch channel sums (BN3 inline) ----------------

__global__ __launch_bounds__(256)
void pointsum_kernel(const _Float16* __restrict__ h3,
                     const int* __restrict__ id0, const int* __restrict__ id1,
                     const float* __restrict__ ss, float* __restrict__ bsum,
                     int N, int Ppb, int bpb, int bs, int PB)
{
    const int bid = blockIdx.x;
    const int s = (bid >> 2) & 1;
    const int pb = (bid >> 3) * 4 + (bid & 3);
    if (pb >= PB) return;
    const int batch = pb / bpb;
    const int blk = pb % bpb;

    const _Float16* __restrict__ h = h3 + (size_t)s * (N + 1) * 16;
    const int* __restrict__ ids = s ? id1 : id0;

    const float* ssp = ss + s * 64;
    float sc[16], sh[16];
    #pragma unroll
    for (int c = 0; c < 16; ++c) { sc[c] = ssp[c]; sh[c] = ssp[32 + c]; }

    float acc[16];
    #pragma unroll
    for (int c = 0; c < 16; ++c) acc[c] = 0.f;

    const int* bid_p = ids + (size_t)batch * Ppb;
    const int base = blk * (256 * 8) + threadIdx.x;
    for (int i = 0; i < 8; ++i) {
        int off = base + i * 256;
        if (off < Ppb) {
            int vx = __builtin_nontemporal_load(bid_p + off);
            const u4* r = (const u4*)(h + (size_t)vx * 16);
            u4 a = r[0], b = r[1];
            h2 x;
            x = bch2(a.x); acc[0] += bnr((float)x.x, sc[0], sh[0]);   acc[1] += bnr((float)x.y, sc[1], sh[1]);
            x = bch2(a.y); acc[2] += bnr((float)x.x, sc[2], sh[2]);   acc[3] += bnr((float)x.y, sc[3], sh[3]);
            x = bch2(a.z); acc[4] += bnr((float)x.x, sc[4], sh[4]);   acc[5] += bnr((float)x.y, sc[5], sh[5]);
            x = bch2(a.w); acc[6] += bnr((float)x.x, sc[6], sh[6]);   acc[7] += bnr((float)x.y, sc[7], sh[7]);
            x = bch2(b.x); acc[8] += bnr((float)x.x, sc[8], sh[8]);   acc[9] += bnr((float)x.y, sc[9], sh[9]);
            x = bch2(b.y); acc[10] += bnr((float)x.x, sc[10], sh[10]); acc[11] += bnr((float)x.y, sc[11], sh[11]);
            x = bch2(b.z); acc[12] += bnr((float)x.x, sc[12], sh[12]); acc[13] += bnr((float)x.y, sc[13], sh[13]);
            x = bch2(b.w); acc[14] += bnr((float)x.x, sc[14], sh[14]); acc[15] += bnr((float)x.y, sc[15], sh[15]);
        }
    }

    #pragma unroll
    for (int c = 0; c < 16; ++c) {
        #pragma unroll
        for (int m = 32; m >= 1; m >>= 1) acc[c] += __shfl_xor(acc[c], m);
    }
    __shared__ float sred[4][16];
    const int lane = threadIdx.x & 63, wid = threadIdx.x >> 6;
    if (lane == 0) {
        #pragma unroll
        for (int c = 0; c < 16; ++c) sred[wid][c] = acc[c];
    }
    __syncthreads();
    if (threadIdx.x < 16) {
        float tot = sred[0][threadIdx.x] + sred[1][threadIdx.x] + sred[2][threadIdx.x] + sred[3][threadIdx.x];
        atomicAdd(&bsum[((size_t)s * bs + batch) * 16 + threadIdx.x], tot);
    }
}

// ---------------- head ----------------

__global__ void final_kernel(const float* __restrict__ bsum,
                             const float* __restrict__ Wg, const float* __restrict__ bg,
                             const float* __restrict__ Wr, const float* __restrict__ br,
                             float* __restrict__ out, int bs, float invP)
{
    const int t = threadIdx.x;
    const int total = 4 * bs * 3;
    if (t < total) {
        const int x = t % 3;
        const int b = (t / 3) % bs;
        const int r = t / (3 * bs);
        const int s = r & 1;
        const float* W = (r < 2) ? Wg : Wr;
        const float* bias = (r < 2) ? bg : br;
        const float* m = bsum + ((size_t)s * bs + b) * 16;
        float a = bias[x];
        #pragma unroll
        for (int c = 0; c < 16; ++c) a = fmaf(m[c] * invP, W[c * 3 + x], a);
        out[t] = a;
    }
}

// ---------------- launch ----------------

extern "C" void kernel_launch(void* const* d_in, const int* in_sizes, int n_in,
                              void* d_out, int out_size, void* d_ws, size_t ws_size,
                              hipStream_t stream)
{
    (void)n_in; (void)ws_size;
    const float* vf0 = (const float*)d_in[0];
    const int*   nb0 = (const int*)d_in[1];
    const int*   id0 = (const int*)d_in[2];
    const float* vf1 = (const float*)d_in[3];
    const int*   nb1 = (const int*)d_in[4];
    const int*   id1 = (const int*)d_in[5];
    const float* W1 = (const float*)d_in[7];
    const float* g1 = (const float*)d_in[8];
    const float* b1 = (const float*)d_in[9];
    const float* W2 = (const float*)d_in[10];
    const float* g2 = (const float*)d_in[11];
    const float* b2 = (const float*)d_in[12];
    const float* W3 = (const float*)d_in[13];
    const float* g3 = (const float*)d_in[14];
    const float* b3 = (const float*)d_in[15];
    const float* Wg = (const float*)d_in[16];
    const float* bg = (const float*)d_in[17];
    const float* Wr = (const float*)d_in[18];
    const float* br = (const float*)d_in[19];

    const int N = in_sizes[0] / 6;
    const int npts = in_sizes[2];
    const int bs = out_size / 12;
    const int Ppb = npts / bs;
    const size_t stride = (size_t)N + 1;

    const int B = (N + 63) / 64;
    const int B4 = ((B + 3) / 4) * 4;

    _Float16* A   = (_Float16*)d_ws;
    _Float16* C   = A + 64 * stride;
    _Float16* D   = C + 64 * stride;
    _Float16* E   = D + 32 * stride;
    _Float16* w1t = E + 32 * stride;
    _Float16* w2t = w1t + KNBR * 16 * 8;
    _Float16* w3t = w2t + 2 * KNBR * 32 * 8;
    float* partials = (float*)(w3t + 4 * KNBR * 16 * 8);   // 2*B*64
    float* mid  = partials + (size_t)2 * B * 64;        // 2*NSA*64
    float* ssb  = mid + 2 * NSA * 64;                   // 128
    float* bsum = ssb + 128;                            // 2*bs*16

    _Float16* fin   = C;
    _Float16* pre1  = C + 16 * stride;
    _Float16* post1 = D;
    _Float16* pre2  = A;
    _Float16* post2 = C;
    _Float16* pre3  = E;

    prep_feats_kernel<<<dim3((unsigned)((stride + 255) / 256), 2), 256, 0, stream>>>(vf0, vf1, fin, N);
    prep_weights_kernel<<<4, 256, 0, stream>>>(W1, W2, W3, w1t, w2t, w3t, bsum, 2 * bs * 16);

    const int cgrid = 2 * B4;

    // conv1: fin -> pre1 (+stats)
    conv8s<16, false, true><<<cgrid, 256, 0, stream>>>(fin, nb0, nb1, w1t, pre1, partials, N, B);
    stats_a_kernel<<<dim3(NSA, 2), 256, 0, stream>>>(partials, mid, B);
    stats_kernel<16><<<dim3(1, 2), 256, 0, stream>>>(mid, N, g1, b1, ssb);
    apply_split_kernel<16><<<dim3((unsigned)((stride * 2 + 255) / 256), 2), 256, 0, stream>>>(pre1, post1, ssb, N);

    // conv2: two 8-ch passes, second accumulates (+stats)
    conv8s<32, false, false><<<cgrid, 256, 0, stream>>>(post1, nb0, nb1, w2t, pre2, nullptr, N, B);
    conv8s<32, true, true><<<cgrid, 256, 0, stream>>>(post1 + 2 * stride * 8, nb0, nb1,
                                                      w2t + KNBR * 32 * 8, pre2, partials, N, B);
    stats_a_kernel<<<dim3(NSA, 2), 256, 0, stream>>>(partials, mid, B);
    stats_kernel<32><<<dim3(1, 2), 256, 0, stream>>>(mid, N, g2, b2, ssb);
    apply_split_kernel<32><<<dim3((unsigned)((stride * 4 + 255) / 256), 2), 256, 0, stream>>>(pre2, post2, ssb, N);

    // conv3: four 8-ch passes, later ones accumulate, last does stats
    conv8s<16, false, false><<<cgrid, 256, 0, stream>>>(post2, nb0, nb1, w3t, pre3, nullptr, N, B);
    conv8s<16, true, false><<<cgrid, 256, 0, stream>>>(post2 + 2 * stride * 8, nb0, nb1,
                                                       w3t + KNBR * 16 * 8, pre3, nullptr, N, B);
    conv8s<16, true, false><<<cgrid, 256, 0, stream>>>(post2 + 4 * stride * 8, nb0, nb1,
                                                       w3t + 2 * KNBR * 16 * 8, pre3, nullptr, N, B);
    conv8s<16, true, true><<<cgrid, 256, 0, stream>>>(post2 + 6 * stride * 8, nb0, nb1,
                                                      w3t + 3 * KNBR * 16 * 8, pre3, partials, N, B);
    stats_a_kernel<<<dim3(NSA, 2), 256, 0, stream>>>(partials, mid, B);
    stats_kernel<16><<<dim3(1, 2), 256, 0, stream>>>(mid, N, g3, b3, ssb);

    const int bpb = (Ppb + 2047) / 2048;
    const int PB = bpb * bs;
    const int PB4 = ((PB + 3) / 4) * 4;
    pointsum_kernel<<<2 * PB4, 256, 0, stream>>>(pre3, id0, id1, ssb, bsum, N, Ppb, bpb, bs, PB);
    final_kernel<<<1, 64, 0, stream>>>(bsum, Wg, bg, Wr, br, (float*)d_out, bs, 1.0f / Ppb);
}